// Round 4
// baseline (118.872 us; speedup 1.0000x reference)
//
#include <hip/hip_runtime.h>
#include <hip/hip_bf16.h>
#include <math.h>

#define N 2048
#define D 512
#define KC 8            // instances per class
#define M (KC - 1)      // positives per row
#define NNEG (N - KC)   // negatives per row
#define ALPHA 4.0f
#define THRESH 0.693f
#define LN2F 0.6931471805599453f
#define INV_LN2F 1.4426950408889634f
#define C2 (THRESH * INV_LN2F)   // validity threshold in log2 domain

typedef unsigned short ushort_t;
using frag_ab = __attribute__((ext_vector_type(8))) short;   // 8 bf16 (4 VGPRs)
using frag_cd = __attribute__((ext_vector_type(4))) float;   // 4 fp32

__device__ __forceinline__ void gload16(const ushort_t* g, ushort_t* l) {
    __builtin_amdgcn_global_load_lds((const __attribute__((address_space(1))) unsigned int*)g,
                                     (__attribute__((address_space(3))) unsigned int*)l, 16, 0, 0);
}

// ---------------- Kernel 1: normalize -> bf16 x, fp32 sq ----------------
// One wave per row, 2048 blocks (8 blocks/CU, 2 waves/SIMD). Pure shfl
// butterfly reduction — no LDS, no barriers. (R3 lesson: the merged 256-block
// norm_gram was 1 wave/SIMD = latency-bound; aux kernels must stay fat-grid.)
__global__ __launch_bounds__(64) void normalize_kernel(const float* __restrict__ in,
                                                       ushort_t* __restrict__ xb,
                                                       float* __restrict__ sq) {
    int row = blockIdx.x;
    int tid = threadIdx.x;               // 64 threads x 2 float4 = 512 elements
    const float4* r4 = (const float4*)(in + (size_t)row * D);
    float4 v0 = r4[tid];
    float4 v1 = r4[tid + 64];
    float p = v0.x * v0.x + v0.y * v0.y + v0.z * v0.z + v0.w * v0.w
            + v1.x * v1.x + v1.y * v1.y + v1.z * v1.z + v1.w * v1.w;
    #pragma unroll
    for (int m = 1; m < 64; m <<= 1) p += __shfl_xor(p, m);
    float scale = ALPHA / sqrtf(p);
    float4 w0 = make_float4(v0.x * scale, v0.y * scale, v0.z * scale, v0.w * scale);
    float4 w1 = make_float4(v1.x * scale, v1.y * scale, v1.z * scale, v1.w * scale);
    float q = w0.x * w0.x + w0.y * w0.y + w0.z * w0.z + w0.w * w0.w
            + w1.x * w1.x + w1.y * w1.y + w1.z * w1.z + w1.w * w1.w;   // fp32 sq, pre-rounding
    __hip_bfloat16 h;
    ushort4 u0, u1;
    h = __float2bfloat16(w0.x); u0.x = *(ushort_t*)&h;
    h = __float2bfloat16(w0.y); u0.y = *(ushort_t*)&h;
    h = __float2bfloat16(w0.z); u0.z = *(ushort_t*)&h;
    h = __float2bfloat16(w0.w); u0.w = *(ushort_t*)&h;
    h = __float2bfloat16(w1.x); u1.x = *(ushort_t*)&h;
    h = __float2bfloat16(w1.y); u1.y = *(ushort_t*)&h;
    h = __float2bfloat16(w1.z); u1.z = *(ushort_t*)&h;
    h = __float2bfloat16(w1.w); u1.w = *(ushort_t*)&h;
    ushort4* xrow = (ushort4*)(xb + (size_t)row * D);
    xrow[tid]      = u0;
    xrow[tid + 64] = u1;
    #pragma unroll
    for (int m = 1; m < 64; m <<= 1) q += __shfl_xor(q, m);
    if (tid == 0) sq[row] = q;
}

// ---------------- Kernel 2: per-class 8x8 Gram -> pos dists -> eprow[N][8] ----------------
// eprow[i][0..6] = exp(pos_dist k) in ascending-j order; eprow[i][7] = sum of pos dists (psum)
// (R0-proven version, restored verbatim.)
#define DP (D + 8)   // +16B row pad: 8 rows land on distinct LDS banks
__global__ __launch_bounds__(64) void posdist_kernel(const ushort_t* __restrict__ xb,
                                                     const float* __restrict__ sq,
                                                     float* __restrict__ eprow) {
    int cls = blockIdx.x;                // 256 classes, 1 wave each
    int tid = threadIdx.x;               // 64
    int base = cls * KC;
    __shared__ ushort_t xl[KC][DP];
    const uint4* src = (const uint4*)(xb + (size_t)base * D);   // 512 x 16B chunks
    #pragma unroll
    for (int c8 = 0; c8 < 8; ++c8) {
        int c = c8 * 64 + tid;           // 0..511
        int r = c >> 6, off = c & 63;    // 64 uint4 per row
        *(uint4*)&xl[r][off * 8] = src[c];
    }
    __syncthreads();
    int i = tid >> 3, j = tid & 7;       // pair (i,j)
    const ushort_t* ri = xl[i];
    const ushort_t* rj = xl[j];
    float acc = 0.f;
    #pragma unroll 2
    for (int d = 0; d < D; d += 8) {
        uint4 ui = *(const uint4*)&ri[d];
        uint4 uj = *(const uint4*)&rj[d];
        unsigned a0 = ui.x, a1 = ui.y, a2 = ui.z, a3 = ui.w;
        unsigned b0 = uj.x, b1 = uj.y, b2 = uj.z, b3 = uj.w;
        acc += __uint_as_float(a0 << 16) * __uint_as_float(b0 << 16);
        acc += __uint_as_float(a0 & 0xffff0000u) * __uint_as_float(b0 & 0xffff0000u);
        acc += __uint_as_float(a1 << 16) * __uint_as_float(b1 << 16);
        acc += __uint_as_float(a1 & 0xffff0000u) * __uint_as_float(b1 & 0xffff0000u);
        acc += __uint_as_float(a2 << 16) * __uint_as_float(b2 << 16);
        acc += __uint_as_float(a2 & 0xffff0000u) * __uint_as_float(b2 & 0xffff0000u);
        acc += __uint_as_float(a3 << 16) * __uint_as_float(b3 << 16);
        acc += __uint_as_float(a3 & 0xffff0000u) * __uint_as_float(b3 & 0xffff0000u);
    }
    float dij = sq[base + i] + sq[base + j] - 2.f * acc;
    float pc = (i == j) ? 0.f : dij;
    #pragma unroll
    for (int m = 1; m < 8; m <<= 1) pc += __shfl_xor(pc, m);   // psum over the 8-lane row group
    if (i != j) {
        int k = j - (j > i ? 1 : 0);
        eprow[(size_t)(base + i) * 8 + k] = __expf(dij);
    }
    if (j == 0) eprow[(size_t)(base + i) * 8 + 7] = pc;
}

// ---------------- Kernel 3: fused dist-GEMM + triplet reduction ----------------
// FROZEN from R3 (byte-identical): 64x64 tile, 2x2 waves, BK=32, dbuf
// global_load_lds, single barrier per K-step, in-register triplet epilogue.
#define TM 64
#define TN 64
#define TK 32
#define NT (D / TK)
#define NBJ (N / TN)   // 32 column-block partials per row

__global__ __launch_bounds__(256) void fused_dist_triplet(const ushort_t* __restrict__ xb,
                                                          const float* __restrict__ sq,
                                                          const float* __restrict__ eprow,
                                                          float4* __restrict__ partial) {
    __shared__ ushort_t As[2 * TM * TK];   // 2 x 4 KB
    __shared__ ushort_t Bs[2 * TN * TK];   // 2 x 4 KB
    __shared__ float eps_lds[TM][8];       // ep0..6 + psum for block rows
    __shared__ float sqr_lds[TM];
    __shared__ float sqc_lds[TN];
    __shared__ float4 comb[2][TM];         // per-wn row partials {s2, cnt, nsum, _}

    int tid  = threadIdx.x;
    int lane = tid & 63;
    int w    = tid >> 6;
    int wm   = w >> 1, wn = w & 1;         // 2x2 wave grid, 32x32 output each
    int quad = lane >> 4, l16 = lane & 15;
    int bi = blockIdx.y, bj = blockIdx.x;

    // Stage per-row ep/sq into LDS (covered by the first __syncthreads)
    if (tid < 128) {
        int rr = tid >> 1, half = (tid & 1) * 4;
        *(float4*)&eps_lds[rr][half] = *(const float4*)(eprow + (size_t)(bi * TM + rr) * 8 + half);
    } else if (tid < 192) {
        sqr_lds[tid - 128] = sq[bi * TM + (tid - 128)];
    } else {
        sqc_lds[tid - 192] = sq[bj * TN + (tid - 192)];
    }

    frag_cd acc[2][2];
    #pragma unroll
    for (int i = 0; i < 2; ++i)
        #pragma unroll
        for (int j = 0; j < 2; ++j)
            acc[i][j] = (frag_cd){0.f, 0.f, 0.f, 0.f};

    // Staging map: tile = 64 rows x 32 k x 2B = 256 x 16B chunks; thread t handles
    // chunk t of A and chunk t of B. LDS dest = chunk*16B -> wave-uniform base + lane*16.
    int r0 = tid >> 2, s0 = (tid & 3) * 8;
    const ushort_t* gA = xb + (size_t)(bi * TM + r0) * D + s0;
    const ushort_t* gB = xb + (size_t)(bj * TN + r0) * D + s0;
    ushort_t* lA = As + tid * 8;
    ushort_t* lB = Bs + tid * 8;

    int aoff[2], boff[2];
    #pragma unroll
    for (int i = 0; i < 2; ++i) {
        aoff[i] = (wm * 32 + i * 16 + l16) * TK + quad * 8;
        boff[i] = (wn * 32 + i * 16 + l16) * TK + quad * 8;
    }

    // Prologue: stage tile 0 into buffer 0
    gload16(gA, lA); gload16(gB, lB);
    int cur = 0;
    for (int t = 0; t < NT; ++t) {
        __syncthreads();   // drains vmcnt(0): buf[cur] ready; prior reads of buf[cur^1] done
        if (t + 1 < NT) {  // stage tile t+1 into the other buffer; overlaps with compute below
            int k0 = (t + 1) * TK;
            int bo = (cur ^ 1) * TM * TK;
            gload16(gA + k0, lA + bo);
            gload16(gB + k0, lB + bo);
        }
        const ushort_t* Ab = As + cur * TM * TK;
        const ushort_t* Bb = Bs + cur * TN * TK;
        frag_ab a[2], b[2];
        #pragma unroll
        for (int i = 0; i < 2; ++i) {
            a[i] = *(const frag_ab*)(Ab + aoff[i]);
            b[i] = *(const frag_ab*)(Bb + boff[i]);
        }
        #pragma unroll
        for (int i = 0; i < 2; ++i)
            #pragma unroll
            for (int j = 0; j < 2; ++j)
                acc[i][j] = __builtin_amdgcn_mfma_f32_16x16x32_bf16(a[i], b[j], acc[i][j], 0, 0, 0);
        cur ^= 1;
    }

    // Epilogue: in-register triplet reduction.
    // C/D layout: col = lane&15 (+j*16 +wn*32), row = quad*4 + reg (+i*16 +wm*32)
    float sjv[2];
    #pragma unroll
    for (int j = 0; j < 2; ++j) sjv[j] = sqc_lds[wn * 32 + j * 16 + l16];
    int colbase = bj * TN + wn * 32 + l16;
    int lr0 = wm * 32 + quad * 4;
    #pragma unroll
    for (int i = 0; i < 2; ++i) {
        #pragma unroll
        for (int r = 0; r < 4; ++r) {
            int lr  = lr0 + i * 16 + r;          // local row 0..63
            int row = bi * TM + lr;
            int cs  = row & ~(KC - 1);           // class block start
            float sr = sqr_lds[lr];
            float4 e0 = *(float4*)&eps_lds[lr][0];
            float4 e1 = *(float4*)&eps_lds[lr][4];
            float epv[7] = {e0.x, e0.y, e0.z, e0.w, e1.x, e1.y, e1.z};
            float s2 = 0.f, ns = 0.f;
            int cnt = 0;
            #pragma unroll
            for (int j = 0; j < 2; ++j) {
                int col = colbase + j * 16;
                if ((unsigned)(col - cs) >= (unsigned)KC) {   // negative pair
                    float neg = sr + sjv[j] - 2.f * acc[i][j][r];
                    ns += neg;
                    float en = __expf(-neg);
                    #pragma unroll
                    for (int k = 0; k < 7; ++k) {
                        float l = __log2f(1.f + epv[k] * en);
                        if (l > C2) { cnt++; s2 += l; }
                    }
                }
            }
            // 16 lanes (same quad) share this row: xor-reduce over lane bits 0..3
            #pragma unroll
            for (int m = 1; m < 16; m <<= 1) {
                s2  += __shfl_xor(s2, m);
                ns  += __shfl_xor(ns, m);
                cnt += __shfl_xor(cnt, m);
            }
            if (l16 == 0) comb[wn][lr] = make_float4(s2, (float)cnt, ns, 0.f);
        }
    }
    __syncthreads();
    if (tid < TM) {
        float4 a0 = comb[0][tid], b0 = comb[1][tid];
        // Row-contiguous layout [row][bj]: final_reduce reads 512B bursts per row.
        partial[(size_t)(bi * TM + tid) * NBJ + bj] =
            make_float4(a0.x + b0.x, a0.y + b0.y, a0.z + b0.z, 0.f);
    }
}

// ---------------- Kernel 4: deterministic final reduction + scalars ----------------
// FROZEN from R3: 512 threads, contiguous 512B-per-row reads, partial unroll.
__global__ __launch_bounds__(512) void final_reduce_kernel(const float4* __restrict__ partial,
                                                           const float* __restrict__ eprow,
                                                           float* __restrict__ out) {
    int tid = threadIdx.x;
    double srm = 0.0, ps = 0.0, nsd = 0.0;
    unsigned long long tot = 0; unsigned zr = 0;
    for (int i = tid; i < N; i += 512) {
        const float4* pr = partial + (size_t)i * NBJ;
        float s2 = 0.f, cf = 0.f, nsum = 0.f;
        #pragma unroll 4
        for (int b = 0; b < NBJ; ++b) {
            float4 pp = pr[b];
            s2 += pp.x; cf += pp.y; nsum += pp.z;
        }
        unsigned c = (unsigned)cf;
        if (c > 0) {
            float row_mean = s2 * LN2F / (float)c;
            srm += (double)row_mean;
            tot += c;
        } else {
            zr++;
        }
        ps  += (double)eprow[(size_t)i * 8 + 7];
        nsd += (double)nsum;
    }
    __shared__ double d0[512], d1[512], d2[512];
    __shared__ unsigned long long dt[512];
    __shared__ unsigned dz[512];
    d0[tid] = srm; d1[tid] = ps; d2[tid] = nsd; dt[tid] = tot; dz[tid] = zr;
    __syncthreads();
    for (int st = 256; st > 0; st >>= 1) {
        if (tid < st) {
            d0[tid] += d0[tid + st]; d1[tid] += d1[tid + st]; d2[tid] += d2[tid + st];
            dt[tid] += dt[tid + st]; dz[tid] += dz[tid + st];
        }
        __syncthreads();
    }
    if (tid == 0) {
        unsigned long long total = dt[0];
        out[0] = (total > 0) ? (float)(d0[0] / (double)total) : 0.f;     // loss
        out[1] = (float)((double)dz[0] / (double)N);                      // accuracy
        out[2] = (float)(d1[0] / (double)((size_t)N * M));                // pos_d
        out[3] = (float)(d2[0] / (double)((size_t)N * NNEG));             // neg_d
    }
}

extern "C" void kernel_launch(void* const* d_in, const int* in_sizes, int n_in,
                              void* d_out, int out_size, void* d_ws, size_t ws_size,
                              hipStream_t stream) {
    const float* inputs = (const float*)d_in[0];
    // targets (d_in[1]) are grouped: [0]*8,[1]*8,... — structure used directly.
    float* out = (float*)d_out;
    char* ws = (char*)d_ws;

    const size_t off_xb = 0;                                             // bf16 x: 2 MB
    const size_t off_sq = off_xb + (size_t)N * D * sizeof(ushort_t);
    const size_t off_ep = off_sq + (size_t)N * sizeof(float);            // eprow: 64 KB
    const size_t off_pp = off_ep + (size_t)N * 8 * sizeof(float);        // partial: 1 MB
    const size_t needed = off_pp + (size_t)N * NBJ * sizeof(float4);
    if (ws_size < needed) return;

    ushort_t* xb      = (ushort_t*)(ws + off_xb);
    float*    sq      = (float*)(ws + off_sq);
    float*    eprow   = (float*)(ws + off_ep);
    float4*   partial = (float4*)(ws + off_pp);

    normalize_kernel<<<N, 64, 0, stream>>>(inputs, xb, sq);
    posdist_kernel<<<N / KC, 64, 0, stream>>>(xb, sq, eprow);
    fused_dist_triplet<<<dim3(N / TN, N / TM), 256, 0, stream>>>(xb, sq, eprow, partial);
    final_reduce_kernel<<<1, 512, 0, stream>>>(partial, eprow, out);
}

// Round 6
// 92.297 us; speedup vs baseline: 1.2879x; 1.2879x over previous
//
#include <hip/hip_runtime.h>
#include <hip/hip_bf16.h>
#include <math.h>

#define N 2048
#define D 512
#define KC 8            // instances per class
#define M (KC - 1)      // positives per row
#define NNEG (N - KC)   // negatives per row
#define ALPHA 4.0f
#define THRESH 0.693f
#define LN2F 0.6931471805599453f
#define INV_LN2F 1.4426950408889634f
#define C2 (THRESH * INV_LN2F)   // validity threshold in log2 domain

typedef unsigned short ushort_t;
using frag_ab = __attribute__((ext_vector_type(8))) short;   // 8 bf16 (4 VGPRs)
using frag_cd = __attribute__((ext_vector_type(4))) float;   // 4 fp32

__device__ __forceinline__ void gload16(const ushort_t* g, ushort_t* l) {
    __builtin_amdgcn_global_load_lds((const __attribute__((address_space(1))) unsigned int*)g,
                                     (__attribute__((address_space(3))) unsigned int*)l, 16, 0, 0);
}

// ---------------- Kernel 1: normalize -> bf16 x, fp32 sq (R0 verbatim) ----------------
__global__ __launch_bounds__(128) void normalize_kernel(const float* __restrict__ in,
                                                        ushort_t* __restrict__ xb,
                                                        float* __restrict__ sq) {
    int row = blockIdx.x;
    int tid = threadIdx.x;               // 128 threads
    const float* r = in + (size_t)row * D;
    float p = 0.f;
    for (int d = tid; d < D; d += 128) { float v = r[d]; p += v * v; }
    __shared__ float red[128];
    red[tid] = p; __syncthreads();
    for (int s = 64; s > 0; s >>= 1) { if (tid < s) red[tid] += red[tid + s]; __syncthreads(); }
    float scale = ALPHA / sqrtf(red[0]);
    __syncthreads();
    float q = 0.f;
    for (int d = tid; d < D; d += 128) {
        float v = r[d] * scale;
        q += v * v;                                  // fp32 sq, pre-rounding (matches reference)
        __hip_bfloat16 h = __float2bfloat16(v);      // RNE
        xb[(size_t)row * D + d] = *(ushort_t*)&h;
    }
    red[tid] = q; __syncthreads();
    for (int s = 64; s > 0; s >>= 1) { if (tid < s) red[tid] += red[tid + s]; __syncthreads(); }
    if (tid == 0) sq[row] = red[0];
}

// ---------------- Kernel 2: dist = sq_i + sq_j - 2 * x.x^T via bf16 MFMA ----------------
// ONLY changed component vs the 95.7us R0 config: 64x64 tile (grid 32x32 = 1024
// blocks -> 4-8 blk/CU vs R0's 128² @ 1 blk/CU), double-buffered global_load_lds,
// single barrier per K-step. Same MFMA shape + TK=32 K-order -> dist bits
// identical to R0's. (R1-R4 evidence: the 64² core with a heavy fused epilogue
// measured >=25us faster than the 128² core with the same epilogue.)
#define TM 64
#define TN 64
#define TK 32
#define NT (D / TK)

__global__ __launch_bounds__(256) void gemm_dist_mfma(const ushort_t* __restrict__ xb,
                                                      const float* __restrict__ sq,
                                                      float* __restrict__ dist) {
    __shared__ ushort_t As[2 * TM * TK];   // 2 x 4 KB
    __shared__ ushort_t Bs[2 * TN * TK];   // 2 x 4 KB
    int tid  = threadIdx.x;
    int lane = tid & 63;
    int w    = tid >> 6;
    int wm   = w >> 1, wn = w & 1;         // 2x2 wave grid, 32x32 output each
    int quad = lane >> 4, l16 = lane & 15;
    int bi = blockIdx.y, bj = blockIdx.x;

    frag_cd acc[2][2];
    #pragma unroll
    for (int i = 0; i < 2; ++i)
        #pragma unroll
        for (int j = 0; j < 2; ++j)
            acc[i][j] = (frag_cd){0.f, 0.f, 0.f, 0.f};

    // Staging map: tile = 64 rows x 32 k x 2B = 256 x 16B chunks; thread t handles
    // chunk t of A and chunk t of B. LDS dest = chunk*16B -> wave-uniform base + lane*16.
    int r0 = tid >> 2, s0 = (tid & 3) * 8;
    const ushort_t* gA = xb + (size_t)(bi * TM + r0) * D + s0;
    const ushort_t* gB = xb + (size_t)(bj * TN + r0) * D + s0;
    ushort_t* lA = As + tid * 8;
    ushort_t* lB = Bs + tid * 8;

    int aoff[2], boff[2];
    #pragma unroll
    for (int i = 0; i < 2; ++i) {
        aoff[i] = (wm * 32 + i * 16 + l16) * TK + quad * 8;
        boff[i] = (wn * 32 + i * 16 + l16) * TK + quad * 8;
    }

    // Prologue: stage tile 0 into buffer 0
    gload16(gA, lA); gload16(gB, lB);
    int cur = 0;
    for (int t = 0; t < NT; ++t) {
        __syncthreads();   // drains vmcnt(0): buf[cur] ready; prior reads of buf[cur^1] done
        if (t + 1 < NT) {  // stage tile t+1 into the other buffer; overlaps with compute below
            int k0 = (t + 1) * TK;
            int bo = (cur ^ 1) * TM * TK;
            gload16(gA + k0, lA + bo);
            gload16(gB + k0, lB + bo);
        }
        const ushort_t* Ab = As + cur * TM * TK;
        const ushort_t* Bb = Bs + cur * TN * TK;
        frag_ab a[2], b[2];
        #pragma unroll
        for (int i = 0; i < 2; ++i) {
            a[i] = *(const frag_ab*)(Ab + aoff[i]);
            b[i] = *(const frag_ab*)(Bb + boff[i]);
        }
        #pragma unroll
        for (int i = 0; i < 2; ++i)
            #pragma unroll
            for (int j = 0; j < 2; ++j)
                acc[i][j] = __builtin_amdgcn_mfma_f32_16x16x32_bf16(a[i], b[j], acc[i][j], 0, 0, 0);
        cur ^= 1;
    }

    // Epilogue: C/D layout col = lane&15, row = quad*4 + reg  [m89/m91 verified]
    int row_base = bi * TM + wm * 32 + quad * 4;
    int col_base = bj * TN + wn * 32 + l16;
    #pragma unroll
    for (int j = 0; j < 2; ++j) {
        int col = col_base + j * 16;
        float sjv = sq[col];
        #pragma unroll
        for (int i = 0; i < 2; ++i) {
            int row = row_base + i * 16;
            #pragma unroll
            for (int r = 0; r < 4; ++r) {
                dist[(size_t)(row + r) * N + col] = sq[row + r] + sjv - 2.f * acc[i][j][r];
            }
        }
    }
}

// ---------------- Kernel 3: per-row triplet reduction (R0 verbatim) ----------------
// rowres[i] = {s2_sum (log2-domain), cnt, psum, nsum}
__global__ __launch_bounds__(256) void triplet_kernel(const float* __restrict__ dist,
                                                      float4* __restrict__ rowres) {
    int i = blockIdx.x;
    int tid = threadIdx.x;
    int cs = (i >> 3) << 3;            // class block start (K=8)
    const float* drow = dist + (size_t)i * N;

    __shared__ float pos[M];
    if (tid == 0) {
        int c = 0;
        for (int j = cs; j < cs + KC; ++j)
            if (j != i) pos[c++] = drow[j];
    }
    __syncthreads();
    float p[M], ep[M];
    #pragma unroll
    for (int k = 0; k < M; ++k) { p[k] = pos[k]; ep[k] = __expf(p[k]); }

    float s2 = 0.f, nsum = 0.f;
    unsigned cnt = 0;
    for (int j = tid; j < N; j += 256) {
        if (j >= cs && j < cs + KC) continue;
        float neg = drow[j];
        nsum += neg;
        float en = __expf(-neg);
        #pragma unroll
        for (int k = 0; k < M; ++k) {
            float e = ep[k] * en;
            float l = __log2f(1.f + e);
            if (l > C2) { cnt++; s2 += l; }
        }
    }

    __shared__ float rs[256];
    __shared__ float rn[256];
    __shared__ unsigned rc[256];
    rs[tid] = s2; rn[tid] = nsum; rc[tid] = cnt;
    __syncthreads();
    for (int st = 128; st > 0; st >>= 1) {
        if (tid < st) { rs[tid] += rs[tid + st]; rn[tid] += rn[tid + st]; rc[tid] += rc[tid + st]; }
        __syncthreads();
    }
    if (tid == 0) {
        float psum = 0.f;
        #pragma unroll
        for (int k = 0; k < M; ++k) psum += p[k];
        rowres[i] = make_float4(rs[0], (float)rc[0], psum, rn[0]);
    }
}

// ---------------- Kernel 4: deterministic final reduction + scalars (R0 verbatim) ----------------
__global__ __launch_bounds__(256) void final_reduce_kernel(const float4* __restrict__ rowres,
                                                           float* __restrict__ out) {
    int tid = threadIdx.x;
    double srm = 0.0, ps = 0.0, ns = 0.0;
    unsigned long long tot = 0; unsigned zr = 0;
    for (int i = tid; i < N; i += 256) {
        float4 r = rowres[i];
        unsigned c = (unsigned)r.y;
        if (c > 0) {
            float row_mean = r.x * LN2F / (float)c;
            srm += (double)row_mean;
            tot += c;
        } else {
            zr++;
        }
        ps += (double)r.z;
        ns += (double)r.w;
    }
    __shared__ double d0[256], d1[256], d2[256];
    __shared__ unsigned long long dt[256];
    __shared__ unsigned dz[256];
    d0[tid] = srm; d1[tid] = ps; d2[tid] = ns; dt[tid] = tot; dz[tid] = zr;
    __syncthreads();
    for (int st = 128; st > 0; st >>= 1) {
        if (tid < st) {
            d0[tid] += d0[tid + st]; d1[tid] += d1[tid + st]; d2[tid] += d2[tid + st];
            dt[tid] += dt[tid + st]; dz[tid] += dz[tid + st];
        }
        __syncthreads();
    }
    if (tid == 0) {
        unsigned long long total = dt[0];
        out[0] = (total > 0) ? (float)(d0[0] / (double)total) : 0.f;     // loss
        out[1] = (float)((double)dz[0] / (double)N);                      // accuracy
        out[2] = (float)(d1[0] / (double)((size_t)N * M));                // pos_d
        out[3] = (float)(d2[0] / (double)((size_t)N * NNEG));             // neg_d
    }
}

extern "C" void kernel_launch(void* const* d_in, const int* in_sizes, int n_in,
                              void* d_out, int out_size, void* d_ws, size_t ws_size,
                              hipStream_t stream) {
    const float* inputs = (const float*)d_in[0];
    // targets (d_in[1]) are grouped: [0]*8,[1]*8,... — structure used directly.
    float* out = (float*)d_out;
    char* ws = (char*)d_ws;

    const size_t off_xb   = 0;                                            // bf16 x: 2 MB
    const size_t off_sq   = off_xb + (size_t)N * D * sizeof(ushort_t);
    const size_t off_dist = off_sq + (size_t)N * sizeof(float) + 4096;    // align
    const size_t off_row  = off_dist + (size_t)N * N * sizeof(float);     // 16 MB
    const size_t needed   = off_row + (size_t)N * sizeof(float4);
    if (ws_size < needed) return;

    ushort_t* xb     = (ushort_t*)(ws + off_xb);
    float*    sq     = (float*)(ws + off_sq);
    float*    dist   = (float*)(ws + off_dist);
    float4*   rowres = (float4*)(ws + off_row);

    normalize_kernel<<<N, 128, 0, stream>>>(inputs, xb, sq);
    gemm_dist_mfma<<<dim3(N / TN, N / TM), 256, 0, stream>>>(xb, sq, dist);
    triplet_kernel<<<N, 256, 0, stream>>>(dist, rowres);
    final_reduce_kernel<<<1, 256, 0, stream>>>(rowres, out);
}